// Round 10
// baseline (377.177 us; speedup 1.0000x reference)
//
#include <hip/hip_runtime.h>
#include <hip/hip_bf16.h>

// CILRS head, MI355X round 10.
// Invariant from r6/r7/r8: global_load_lds fill saturates ~16 B/cyc/CU; r8
// pushed ~1.1 GB through it (every block staged the full weight panel).
// Fix: B is per-wave-private -> direct global->reg with ONE-SECTION-AHEAD
// prefetch (r7's fix); only the shared A tile uses gll (165 MB chip-wide).
// One fused kernel: 512 thr / 8 waves (0-3 branch, 4-7 speed), M=64, N=512,
// acc[4][4]/wave, Y+h2 in 64KB LDS overlay (k2 + Yg roundtrip eliminated).
// launch_bounds(512,2): budget 256 regs, est ~160 used (r3/r4/r9 spill rule).
// ws layout (bytes):
//   0        spb      : B*128 bf16 sp-latent (16,777,216)
//   16777216 perm     : (B+384) int32
//   17040896 bcnt     : [1024][6] int
//   17065472 chunkoff : [1024][6] int
//   17090048 pad      : pad[0..6]=offsets, pad[8+g]=totals
//   17090304 Wsi2T / 17155840 Wso1T / 17483520 Wso2T / 17614592 Wb1T /
//   19580672 Wb2T  (end 20,367,104)

#define NB 65536

typedef __attribute__((ext_vector_type(8))) short short8;
typedef __attribute__((ext_vector_type(4))) float f32x4;
typedef unsigned short bhalf;
typedef unsigned int u32;

__device__ __forceinline__ bhalf f2b(float x) {
    __hip_bfloat16 h = __float2bfloat16(x);
    return *reinterpret_cast<bhalf*>(&h);
}
__device__ __forceinline__ void gll16(const void* g, void* l) {
    __builtin_amdgcn_global_load_lds(
        (const __attribute__((address_space(1))) u32*)g,
        (__attribute__((address_space(3))) u32*)l, 16, 0, 0);
}
// 64B-row bf16 tiles: phys = row*64 + (cb ^ (((row>>1)&3)<<4))
__device__ __forceinline__ int sadr(int row, int cb) {
    return row * 64 + (cb ^ (((row >> 1) & 3) << 4));
}
// 1024B-row tile (Y/h2 overlay, 512 cols bf16)
__device__ __forceinline__ int yadr2(int row, int cb) {
    return row * 1024 + (cb ^ ((row & 7) << 4));
}
__device__ __forceinline__ void wvm5()  { asm volatile("s_waitcnt vmcnt(5)"  ::: "memory"); }
__device__ __forceinline__ void wvm0()  { asm volatile("s_waitcnt vmcnt(0)"  ::: "memory"); }
__device__ __forceinline__ void wlgkm0(){ asm volatile("s_waitcnt lgkmcnt(0)" ::: "memory"); }

// -------- weight transpose, 64x64 LDS tiles --------
__global__ __launch_bounds__(256) void k_wprep(
    const float* __restrict__ Wsi2, const float* __restrict__ Wso1,
    const float* __restrict__ Wso2, const float* __restrict__ Wb1,
    const float* __restrict__ Wb2,
    bhalf* __restrict__ Wsi2T, bhalf* __restrict__ Wso1T,
    bhalf* __restrict__ Wso2T, bhalf* __restrict__ Wb1T,
    bhalf* __restrict__ Wb2T) {
    __shared__ float T[64][65];
    const int id = blockIdx.x, t = threadIdx.x;
    const float* src; bhalf* dst; int K, N, tk, tn, b;
    if (id < 8)        { src = Wsi2; dst = Wsi2T; K = 256; N = 128; b = 0; int tl = id;      tk = tl / 2; tn = tl % 2; }
    else if (id < 48)  { src = Wso1; dst = Wso1T; K = 640; N = 256; b = 0; int tl = id - 8;  tk = tl / 4; tn = tl % 4; }
    else if (id < 64)  { src = Wso2; dst = Wso2T; K = 256; N = 256; b = 0; int tl = id - 48; tk = tl / 4; tn = tl % 4; }
    else if (id < 304) { src = Wb1;  dst = Wb1T;  K = 640; N = 256; int li = id - 64;  b = li / 40; int tl = li % 40; tk = tl / 4; tn = tl % 4; }
    else               { src = Wb2;  dst = Wb2T;  K = 256; N = 256; int li = id - 304; b = li / 16; int tl = li % 16; tk = tl / 4; tn = tl % 4; }
    const int k0 = tk * 64, n0 = tn * 64;
    src += (size_t)b * K * N; dst += (size_t)b * N * K;
    const int c = t & 63, r0 = t >> 6;
#pragma unroll
    for (int j = 0; j < 16; ++j) {
        int r = r0 + j * 4;
        T[r][c] = src[(size_t)(k0 + r) * N + n0 + c];
    }
    __syncthreads();
#pragma unroll
    for (int j = 0; j < 16; ++j) {
        int r = r0 + j * 4;
        dst[(size_t)(n0 + r) * K + k0 + c] = f2b(T[c][r]);
    }
}

// speed-latent + per-chunk command counts (NO atomics)
__global__ __launch_bounds__(256) void k_prep(
    const float* __restrict__ speed, const float* __restrict__ Wsi1,
    const float* __restrict__ bsi1, const bhalf* __restrict__ Wsi2T,
    const float* __restrict__ bsi2, const int* __restrict__ cmd,
    bhalf* __restrict__ spb, int* __restrict__ bcnt) {
    __shared__ bhalf A[64 * 72];
    __shared__ bhalf BT[128 * 72];
    const int t = threadIdx.x, lane = t & 63, wid = t >> 6;
    const int rbase = blockIdx.x * 64;
    if (wid == 0) {
        int c = cmd[rbase + lane] - 1;
        int v = 0;
#pragma unroll
        for (int g = 0; g < 6; ++g) {
            unsigned long long m = __ballot(c == g);
            if (lane == g) v = (int)__popcll(m);
        }
        if (lane < 6) bcnt[blockIdx.x * 6 + lane] = v;
    }
    const int wm = wid >> 1, wn = wid & 1;
    f32x4 acc[2][4];
    for (int m = 0; m < 2; ++m) for (int n = 0; n < 4; ++n)
        for (int r = 0; r < 4; ++r) acc[m][n][r] = 0.f;
    const int ar = t >> 2, kp = (t & 3) * 16;
    const float s = speed[rbase + ar];
    for (int kc = 0; kc < 4; ++kc) {
        short8 w0, w1;
#pragma unroll
        for (int j = 0; j < 8; ++j) {
            int k = kc * 64 + kp + j;
            w0[j] = (short)f2b(fmaxf(fmaf(s, Wsi1[k], bsi1[k]), 0.f));
            w1[j] = (short)f2b(fmaxf(fmaf(s, Wsi1[k + 8], bsi1[k + 8]), 0.f));
        }
        *(short8*)&A[ar * 72 + kp] = w0;
        *(short8*)&A[ar * 72 + kp + 8] = w1;
#pragma unroll
        for (int j = 0; j < 4; ++j) {
            int ch = t + j * 256;
            int n2 = ch >> 3, ko = (ch & 7) * 8;
            *(short8*)&BT[n2 * 72 + ko] =
                *(const short8*)(Wsi2T + n2 * 256 + kc * 64 + ko);
        }
        __syncthreads();
#pragma unroll
        for (int ks = 0; ks < 2; ++ks) {
            short8 a[2], b[4];
#pragma unroll
            for (int m = 0; m < 2; ++m)
                a[m] = *(const short8*)&A[(wm * 32 + m * 16 + (lane & 15)) * 72 + ks * 32 + (lane >> 4) * 8];
#pragma unroll
            for (int n = 0; n < 4; ++n)
                b[n] = *(const short8*)&BT[(wn * 64 + n * 16 + (lane & 15)) * 72 + ks * 32 + (lane >> 4) * 8];
#pragma unroll
            for (int m = 0; m < 2; ++m)
#pragma unroll
                for (int n = 0; n < 4; ++n)
                    acc[m][n] = __builtin_amdgcn_mfma_f32_16x16x32_bf16(a[m], b[n], acc[m][n], 0, 0, 0);
        }
        __syncthreads();
    }
#pragma unroll
    for (int m = 0; m < 2; ++m)
#pragma unroll
    for (int n = 0; n < 4; ++n) {
        int col = wn * 64 + n * 16 + (lane & 15);
        float bias = bsi2[col];
#pragma unroll
        for (int r = 0; r < 4; ++r) {
            int row = rbase + wm * 32 + m * 16 + (lane >> 4) * 4 + r;
            spb[row * 128 + col] = f2b(acc[m][n][r] + bias);
        }
    }
}

__global__ __launch_bounds__(1024) void k_scan(
    const int* __restrict__ bcnt, int* __restrict__ chunkoff,
    int* __restrict__ pad) {
    __shared__ int sc[1024];
    __shared__ int tot[8];
    __shared__ int spo[8];
    const int t = threadIdx.x;
    for (int g = 0; g < 6; ++g) {
        int v = bcnt[t * 6 + g];
        sc[t] = v;
        __syncthreads();
        for (int s = 1; s < 1024; s <<= 1) {
            int u = (t >= s) ? sc[t - s] : 0;
            __syncthreads();
            sc[t] += u;
            __syncthreads();
        }
        if (t == 1023) tot[g] = sc[t];
        chunkoff[t * 6 + g] = sc[t] - v;
        __syncthreads();
    }
    if (t == 0) {
        int off = 0;
        for (int g = 0; g < 6; ++g) {
            spo[g] = off; pad[g] = off; pad[8 + g] = tot[g];
            off += ((tot[g] + 63) >> 6) << 6;
        }
        spo[6] = off; pad[6] = off;
    }
    __syncthreads();
    for (int g = 0; g < 6; ++g) chunkoff[t * 6 + g] += spo[g];
}

__global__ __launch_bounds__(256) void k_scatter(
    const int* __restrict__ cmd, const int* __restrict__ chunkoff,
    int* __restrict__ perm) {
    const int lane = threadIdx.x & 63, w = threadIdx.x >> 6;
    const int chunk = blockIdx.x * 4 + w;
    const int idx = chunk * 64 + lane;
    const int c = cmd[idx] - 1;
#pragma unroll
    for (int g = 0; g < 6; ++g) {
        unsigned long long m = __ballot(c == g);
        if (c == g) {
            int pos = chunkoff[chunk * 6 + g] + (int)__popcll(m & ((1ull << lane) - 1ull));
            perm[pos] = idx;
        }
    }
}

// ===== k3: fused 3 layers, both heads. 512 thr / 8 waves. A via gll-dbuf,
// ===== B direct global->reg prefetched 1 section ahead. Y/h2 in LDS. =======
__global__ __launch_bounds__(512, 2) void k3(
    const float* __restrict__ emb, const bhalf* __restrict__ spb,
    const bhalf* __restrict__ Wso1T, const float* __restrict__ bso1,
    const bhalf* __restrict__ Wso2T, const float* __restrict__ bso2,
    const float* __restrict__ Wso3, const float* __restrict__ bso3,
    const bhalf* __restrict__ Wb1T, const float* __restrict__ bb1,
    const bhalf* __restrict__ Wb2T, const float* __restrict__ bb2,
    const float* __restrict__ Wb3, const float* __restrict__ bb3,
    const int* __restrict__ pad, const int* __restrict__ perm,
    float* __restrict__ out) {
    __shared__ __align__(16) char L[81920];
    char* const SA0 = L;           // 2 x 8192 A dbuf
    char* const Yb  = L + 16384;   // [64 rows][512 cols bf16] swizzled
    const int t = threadIdx.x, lane = t & 63, wid = t >> 6;
    const int head = wid >> 2, wn = wid & 3;
    const int pad6 = pad[6];
    const int arow = lane & 15, kb = (lane >> 4) * 16;
    const int rowA = t >> 3;
    const int lcA = ((t & 7) * 16) ^ ((rowA & 7) << 4);
    const int rowS = (t & 255) >> 2;
    const int lcS = ((t & 3) * 16) ^ (((rowS >> 1) & 3) << 4);
    const int dstA = t * 16;
    const int spdst = (t < 256) ? (t * 16) : (4096 + (t - 256) * 16);

    const bhalf* W1h = head ? Wso1T : Wb1T;
    const bhalf* W2h = head ? Wso2T : Wb2T;
    const float* b1h = head ? bso1 : bb1;
    const float* b2h = head ? bso2 : bb2;
    const float* W3h = head ? Wso3 : Wb3;
    const float* b3h = head ? bso3 : bb3;
    const int DOUT = head ? 1 : 3;
    const int col0 = wn * 64 + arow;   // + n*16 within head

    for (int tile = blockIdx.x; tile * 64 < pad6; tile += 1024) {
        const int tstart = tile * 64;
        int g = 0;
        while (pad[g + 1] <= tstart) ++g;
        const int gbase = pad[g], gcnt = pad[8 + g];
        const int goff = head ? 0 : g;
        const bhalf* W1T = W1h + (size_t)goff * (256 * 640);
        const bhalf* W2T = W2h + (size_t)goff * (256 * 256);
        const float* b1p = b1h + goff * 256;
        const float* b2p = b2h + goff * 256;
        const float* W3p = W3h + (size_t)goff * (256 * 3);
        const float* b3p = b3h + goff * 3;

        const int pA = tstart + rowA;
        const int rA = ((pA - gbase) < gcnt) ? perm[pA] : 0;
        const int pS = tstart + rowS;
        const int rS = ((pS - gbase) < gcnt) ? perm[pS] : 0;
        const char* embp = (const char*)(emb + (size_t)rA * 512);
        const char* spbp = (const char*)(spb + (size_t)rS * 128);
        const char* bp1_0 = (const char*)W1T + (size_t)(col0 +  0) * 1280 + kb;
        const char* bp1_1 = (const char*)W1T + (size_t)(col0 + 16) * 1280 + kb;
        const char* bp1_2 = (const char*)W1T + (size_t)(col0 + 32) * 1280 + kb;
        const char* bp1_3 = (const char*)W1T + (size_t)(col0 + 48) * 1280 + kb;

        float bi1[4], bi2[4];
#pragma unroll
        for (int n = 0; n < 4; ++n) {
            bi1[n] = b1p[col0 + n * 16];
            bi2[n] = b2p[col0 + n * 16];
        }

        f32x4 acc[4][4];
#pragma unroll
        for (int m = 0; m < 4; ++m)
#pragma unroll
            for (int n = 0; n < 4; ++n)
#pragma unroll
                for (int r = 0; r < 4; ++r) acc[m][n][r] = 0.f;

#define ST_A3(KN, BUF) do { int kn_ = (KN);                                      \
        if (kn_ < 16) gll16(embp + kn_ * 128 + lcA, SA0 + (BUF) * 8192 + dstA);  \
        else          gll16(spbp + (kn_ - 16) * 64 + lcS, SA0 + (BUF) * 8192 + spdst); \
    } while (0)

        // ---------------- layer 1: K=640, 20 sections ----------------
        short8 bc0 = *(const short8*)(bp1_0);
        short8 bc1 = *(const short8*)(bp1_1);
        short8 bc2 = *(const short8*)(bp1_2);
        short8 bc3 = *(const short8*)(bp1_3);
        ST_A3(0, 0);
#pragma unroll 2
        for (int kc = 0; kc < 20; ++kc) {
            const int buf = kc & 1;
            short8 bn0, bn1, bn2, bn3;
            if (kc < 19) {
                bn0 = *(const short8*)(bp1_0 + (kc + 1) * 64);
                bn1 = *(const short8*)(bp1_1 + (kc + 1) * 64);
                bn2 = *(const short8*)(bp1_2 + (kc + 1) * 64);
                bn3 = *(const short8*)(bp1_3 + (kc + 1) * 64);
                ST_A3(kc + 1, buf ^ 1);
                wvm5();                        // 4 B-loads + 1 gll newest
            } else {
                wvm0();
            }
            __builtin_amdgcn_s_barrier();
            const char* SAc = SA0 + buf * 8192;
            short8 a[4];
            if (kc < 16) {
#pragma unroll
                for (int m = 0; m < 4; ++m) {
                    int row = m * 16 + arow;
                    int sw = (row & 7) << 4;
                    int c0 = (lane >> 4) * 32;
                    float4 f0 = *(const float4*)(SAc + row * 128 + (c0 ^ sw));
                    float4 f1 = *(const float4*)(SAc + row * 128 + ((c0 + 16) ^ sw));
                    a[m][0] = (short)f2b(f0.x); a[m][1] = (short)f2b(f0.y);
                    a[m][2] = (short)f2b(f0.z); a[m][3] = (short)f2b(f0.w);
                    a[m][4] = (short)f2b(f1.x); a[m][5] = (short)f2b(f1.y);
                    a[m][6] = (short)f2b(f1.z); a[m][7] = (short)f2b(f1.w);
                }
            } else {
#pragma unroll
                for (int m = 0; m < 4; ++m)
                    a[m] = *(const short8*)(SAc + sadr(m * 16 + arow, kb));
            }
#pragma unroll
            for (int m = 0; m < 4; ++m) {
                acc[m][0] = __builtin_amdgcn_mfma_f32_16x16x32_bf16(a[m], bc0, acc[m][0], 0, 0, 0);
                acc[m][1] = __builtin_amdgcn_mfma_f32_16x16x32_bf16(a[m], bc1, acc[m][1], 0, 0, 0);
                acc[m][2] = __builtin_amdgcn_mfma_f32_16x16x32_bf16(a[m], bc2, acc[m][2], 0, 0, 0);
                acc[m][3] = __builtin_amdgcn_mfma_f32_16x16x32_bf16(a[m], bc3, acc[m][3], 0, 0, 0);
            }
            if (kc < 19) { bc0 = bn0; bc1 = bn1; bc2 = bn2; bc3 = bn3; }
            __builtin_amdgcn_s_barrier();
        }
        // issue L2 B sec-0 early (hides L2 latency under epilogue-1)
        const char* bp2_0 = (const char*)W2T + (size_t)(col0 +  0) * 512 + kb;
        const char* bp2_1 = (const char*)W2T + (size_t)(col0 + 16) * 512 + kb;
        const char* bp2_2 = (const char*)W2T + (size_t)(col0 + 32) * 512 + kb;
        const char* bp2_3 = (const char*)W2T + (size_t)(col0 + 48) * 512 + kb;
        short8 c0 = *(const short8*)(bp2_0);
        short8 c1 = *(const short8*)(bp2_1);
        short8 c2 = *(const short8*)(bp2_2);
        short8 c3 = *(const short8*)(bp2_3);
        // epi 1: bias+relu -> Yb
#pragma unroll
        for (int m = 0; m < 4; ++m)
#pragma unroll
        for (int n = 0; n < 4; ++n) {
            int col = wid * 64 + n * 16 + arow;    // 0..511
#pragma unroll
            for (int r = 0; r < 4; ++r) {
                int row = m * 16 + (lane >> 4) * 4 + r;
                *(bhalf*)(Yb + yadr2(row, 2 * col)) = f2b(fmaxf(acc[m][n][r] + bi1[n], 0.f));
                acc[m][n][r] = 0.f;
            }
        }
        wlgkm0();
        __builtin_amdgcn_s_barrier();
        // ---------------- layer 2: K=256, 8 sections, no barriers ----------
        for (int kc = 0; kc < 8; ++kc) {
            short8 d0, d1, d2, d3;
            if (kc < 7) {
                d0 = *(const short8*)(bp2_0 + (kc + 1) * 64);
                d1 = *(const short8*)(bp2_1 + (kc + 1) * 64);
                d2 = *(const short8*)(bp2_2 + (kc + 1) * 64);
                d3 = *(const short8*)(bp2_3 + (kc + 1) * 64);
            }
            short8 a[4];
#pragma unroll
            for (int m = 0; m < 4; ++m)
                a[m] = *(const short8*)(Yb + yadr2(m * 16 + arow, head * 512 + kc * 64 + kb));
#pragma unroll
            for (int m = 0; m < 4; ++m) {
                acc[m][0] = __builtin_amdgcn_mfma_f32_16x16x32_bf16(a[m], c0, acc[m][0], 0, 0, 0);
                acc[m][1] = __builtin_amdgcn_mfma_f32_16x16x32_bf16(a[m], c1, acc[m][1], 0, 0, 0);
                acc[m][2] = __builtin_amdgcn_mfma_f32_16x16x32_bf16(a[m], c2, acc[m][2], 0, 0, 0);
                acc[m][3] = __builtin_amdgcn_mfma_f32_16x16x32_bf16(a[m], c3, acc[m][3], 0, 0, 0);
            }
            if (kc < 7) { c0 = d0; c1 = d1; c2 = d2; c3 = d3; }
        }
        __builtin_amdgcn_s_barrier();          // all waves done reading Yb
        // epi 2: bias+relu -> h2 over Yb
#pragma unroll
        for (int m = 0; m < 4; ++m)
#pragma unroll
        for (int n = 0; n < 4; ++n) {
            int col = wid * 64 + n * 16 + arow;
#pragma unroll
            for (int r = 0; r < 4; ++r) {
                int row = m * 16 + (lane >> 4) * 4 + r;
                *(bhalf*)(Yb + yadr2(row, 2 * col)) = f2b(fmaxf(acc[m][n][r] + bi2[n], 0.f));
            }
        }
        wlgkm0();
        __builtin_amdgcn_s_barrier();
        // ---------------- layer 3: wave w -> head w>>2, rows (w&3)*16.. -----
        f32x4 z;
#pragma unroll
        for (int r = 0; r < 4; ++r) z[r] = 0.f;
        const int col3 = arow;
        const int rbase3 = wn * 16;
        for (int kc = 0; kc < 8; ++kc) {
            short8 a3 = *(const short8*)(Yb + yadr2(rbase3 + arow, head * 512 + kc * 64 + kb));
            short8 bw;
#pragma unroll
            for (int j = 0; j < 8; ++j) bw[j] = 0;
            if (col3 < DOUT) {
                int kq = kc * 32 + (lane >> 4) * 8;
#pragma unroll
                for (int j = 0; j < 8; ++j)
                    bw[j] = (short)f2b(W3p[(kq + j) * DOUT + col3]);
            }
            z = __builtin_amdgcn_mfma_f32_16x16x32_bf16(a3, bw, z, 0, 0, 0);
        }
        if (col3 < DOUT) {
            float bias = b3p[col3];
#pragma unroll
            for (int rr = 0; rr < 4; ++rr) {
                int r = rbase3 + (lane >> 4) * 4 + rr;
                int p2 = tstart + r;
                if ((p2 - gbase) < gcnt) {
                    int ro = perm[p2];
                    float v = z[rr] + bias;
                    if (head == 0) out[(size_t)ro * 3 + col3] = 1.f / (1.f + __expf(-v));
                    else           out[(size_t)NB * 3 + ro] = v;
                }
            }
        }
        __builtin_amdgcn_s_barrier();          // end-of-tile
#undef ST_A3
    }
}

extern "C" void kernel_launch(void* const* d_in, const int* in_sizes, int n_in,
                              void* d_out, int out_size, void* d_ws, size_t ws_size,
                              hipStream_t stream) {
    (void)in_sizes; (void)n_in; (void)out_size; (void)ws_size;
    const float* emb   = (const float*)d_in[0];
    const float* speed = (const float*)d_in[1];
    const int*   cmd   = (const int*)d_in[2];
    const float* Wsi1  = (const float*)d_in[3];
    const float* bsi1  = (const float*)d_in[4];
    const float* Wsi2  = (const float*)d_in[5];
    const float* bsi2  = (const float*)d_in[6];
    const float* Wso1  = (const float*)d_in[7];
    const float* bso1  = (const float*)d_in[8];
    const float* Wso2  = (const float*)d_in[9];
    const float* bso2  = (const float*)d_in[10];
    const float* Wso3  = (const float*)d_in[11];
    const float* bso3  = (const float*)d_in[12];
    const float* Wb1   = (const float*)d_in[13];
    const float* bb1   = (const float*)d_in[14];
    const float* Wb2   = (const float*)d_in[15];
    const float* bb2   = (const float*)d_in[16];
    const float* Wb3   = (const float*)d_in[17];
    const float* bb3   = (const float*)d_in[18];
    float* out = (float*)d_out;

    char* ws = (char*)d_ws;
    bhalf* spb      = (bhalf*)(ws);
    int*   perm     = (int*)(ws + 16777216);
    int*   bcnt     = (int*)(ws + 17040896);
    int*   chunkoff = (int*)(ws + 17065472);
    int*   pad      = (int*)(ws + 17090048);
    bhalf* Wsi2T    = (bhalf*)(ws + 17090304);
    bhalf* Wso1T    = (bhalf*)(ws + 17155840);
    bhalf* Wso2T    = (bhalf*)(ws + 17483520);
    bhalf* Wb1T     = (bhalf*)(ws + 17614592);
    bhalf* Wb2T     = (bhalf*)(ws + 19580672);

    k_wprep<<<400, 256, 0, stream>>>(Wsi2, Wso1, Wso2, Wb1, Wb2,
                                     Wsi2T, Wso1T, Wso2T, Wb1T, Wb2T);
    k_prep<<<NB / 64, 256, 0, stream>>>(speed, Wsi1, bsi1, Wsi2T, bsi2, cmd,
                                        spb, bcnt);
    k_scan<<<1, 1024, 0, stream>>>(bcnt, chunkoff, pad);
    k_scatter<<<NB / 256, 256, 0, stream>>>(cmd, chunkoff, perm);
    k3<<<1024, 512, 0, stream>>>(emb, spb,
                                 Wso1T, bso1, Wso2T, bso2, Wso3, bso3,
                                 Wb1T, bb1, Wb2T, bb2, Wb3, bb3,
                                 pad, perm, out);
}

// Round 12
// 186.169 us; speedup vs baseline: 2.0260x; 2.0260x over previous
//
#include <hip/hip_runtime.h>
#include <hip/hip_bf16.h>

// CILRS head, MI355X round 12 = round 11 + kc==0 vmcnt race fix.
// r11 bug: vmcnt retires FIFO; at kc==0 the newest-6 window (wvm6) left the
// SA[0] gll DMA un-waited (outstanding stack [bi(8), bc(4), gll0(2), gll1(2)])
// -> section-0 A read mid-DMA -> replay-timing-dependent divergence.
// Fix: first iteration waits wvm2 (only gll1 may remain in flight).
// Structure: 256 thr, 64x256 tile, 3 blocks/CU. A via gll-dbuf (8KB/section,
// counted vmcnt); B frags global->reg, reloaded in place after last MFMA use.
// Layer 2: zero staging, zero in-loop barriers.
// ws layout (bytes):
//   0        spb      : B*128 bf16 sp-latent (16,777,216)
//   16777216 perm     : (B+384) int32
//   17040896 bcnt     : [1024][6] int
//   17065472 chunkoff : [1024][6] int
//   17090048 pad      : pad[0..6]=offsets, pad[8+g]=totals
//   17090304 Wsi2T / 17155840 Wso1T / 17483520 Wso2T / 17614592 Wb1T /
//   19580672 Wb2T  (end 20,367,104)

#define NB 65536
#define NBRB 1030   // branch-region blocks; speed region follows

typedef __attribute__((ext_vector_type(8))) short short8;
typedef __attribute__((ext_vector_type(4))) float f32x4;
typedef unsigned short bhalf;
typedef unsigned int u32;

__device__ __forceinline__ bhalf f2b(float x) {
    __hip_bfloat16 h = __float2bfloat16(x);
    return *reinterpret_cast<bhalf*>(&h);
}
__device__ __forceinline__ void gll16(const void* g, void* l) {
    __builtin_amdgcn_global_load_lds(
        (const __attribute__((address_space(1))) u32*)g,
        (__attribute__((address_space(3))) u32*)l, 16, 0, 0);
}
// 64B-row bf16 tile (sp-A): phys = row*64 + (cb ^ (((row>>1)&3)<<4))
__device__ __forceinline__ int sadr(int row, int cb) {
    return row * 64 + (cb ^ (((row >> 1) & 3) << 4));
}
// 512B-row tile (Y): phys = row*512 + (cb ^ ((row&7)<<4))
__device__ __forceinline__ int yadr(int row, int cb) {
    return row * 512 + (cb ^ ((row & 7) << 4));
}
__device__ __forceinline__ void wvm6()  { asm volatile("s_waitcnt vmcnt(6)"  ::: "memory"); }
__device__ __forceinline__ void wvm4()  { asm volatile("s_waitcnt vmcnt(4)"  ::: "memory"); }
__device__ __forceinline__ void wvm2()  { asm volatile("s_waitcnt vmcnt(2)"  ::: "memory"); }
__device__ __forceinline__ void wlgkm0(){ asm volatile("s_waitcnt lgkmcnt(0)" ::: "memory"); }

// -------- weight transpose, 64x64 LDS tiles --------
__global__ __launch_bounds__(256) void k_wprep(
    const float* __restrict__ Wsi2, const float* __restrict__ Wso1,
    const float* __restrict__ Wso2, const float* __restrict__ Wb1,
    const float* __restrict__ Wb2,
    bhalf* __restrict__ Wsi2T, bhalf* __restrict__ Wso1T,
    bhalf* __restrict__ Wso2T, bhalf* __restrict__ Wb1T,
    bhalf* __restrict__ Wb2T) {
    __shared__ float T[64][65];
    const int id = blockIdx.x, t = threadIdx.x;
    const float* src; bhalf* dst; int K, N, tk, tn, b;
    if (id < 8)        { src = Wsi2; dst = Wsi2T; K = 256; N = 128; b = 0; int tl = id;      tk = tl / 2; tn = tl % 2; }
    else if (id < 48)  { src = Wso1; dst = Wso1T; K = 640; N = 256; b = 0; int tl = id - 8;  tk = tl / 4; tn = tl % 4; }
    else if (id < 64)  { src = Wso2; dst = Wso2T; K = 256; N = 256; b = 0; int tl = id - 48; tk = tl / 4; tn = tl % 4; }
    else if (id < 304) { src = Wb1;  dst = Wb1T;  K = 640; N = 256; int li = id - 64;  b = li / 40; int tl = li % 40; tk = tl / 4; tn = tl % 4; }
    else               { src = Wb2;  dst = Wb2T;  K = 256; N = 256; int li = id - 304; b = li / 16; int tl = li % 16; tk = tl / 4; tn = tl % 4; }
    const int k0 = tk * 64, n0 = tn * 64;
    src += (size_t)b * K * N; dst += (size_t)b * N * K;
    const int c = t & 63, r0 = t >> 6;
#pragma unroll
    for (int j = 0; j < 16; ++j) {
        int r = r0 + j * 4;
        T[r][c] = src[(size_t)(k0 + r) * N + n0 + c];
    }
    __syncthreads();
#pragma unroll
    for (int j = 0; j < 16; ++j) {
        int r = r0 + j * 4;
        dst[(size_t)(n0 + r) * K + k0 + c] = f2b(T[c][r]);
    }
}

// speed-latent + per-chunk command counts (NO atomics)
__global__ __launch_bounds__(256) void k_prep(
    const float* __restrict__ speed, const float* __restrict__ Wsi1,
    const float* __restrict__ bsi1, const bhalf* __restrict__ Wsi2T,
    const float* __restrict__ bsi2, const int* __restrict__ cmd,
    bhalf* __restrict__ spb, int* __restrict__ bcnt) {
    __shared__ bhalf A[64 * 72];
    __shared__ bhalf BT[128 * 72];
    const int t = threadIdx.x, lane = t & 63, wid = t >> 6;
    const int rbase = blockIdx.x * 64;
    if (wid == 0) {
        int c = cmd[rbase + lane] - 1;
        int v = 0;
#pragma unroll
        for (int g = 0; g < 6; ++g) {
            unsigned long long m = __ballot(c == g);
            if (lane == g) v = (int)__popcll(m);
        }
        if (lane < 6) bcnt[blockIdx.x * 6 + lane] = v;
    }
    const int wm = wid >> 1, wn = wid & 1;
    f32x4 acc[2][4];
    for (int m = 0; m < 2; ++m) for (int n = 0; n < 4; ++n)
        for (int r = 0; r < 4; ++r) acc[m][n][r] = 0.f;
    const int ar = t >> 2, kp = (t & 3) * 16;
    const float s = speed[rbase + ar];
    for (int kc = 0; kc < 4; ++kc) {
        short8 w0, w1;
#pragma unroll
        for (int j = 0; j < 8; ++j) {
            int k = kc * 64 + kp + j;
            w0[j] = (short)f2b(fmaxf(fmaf(s, Wsi1[k], bsi1[k]), 0.f));
            w1[j] = (short)f2b(fmaxf(fmaf(s, Wsi1[k + 8], bsi1[k + 8]), 0.f));
        }
        *(short8*)&A[ar * 72 + kp] = w0;
        *(short8*)&A[ar * 72 + kp + 8] = w1;
#pragma unroll
        for (int j = 0; j < 4; ++j) {
            int ch = t + j * 256;
            int n2 = ch >> 3, ko = (ch & 7) * 8;
            *(short8*)&BT[n2 * 72 + ko] =
                *(const short8*)(Wsi2T + n2 * 256 + kc * 64 + ko);
        }
        __syncthreads();
#pragma unroll
        for (int ks = 0; ks < 2; ++ks) {
            short8 a[2], b[4];
#pragma unroll
            for (int m = 0; m < 2; ++m)
                a[m] = *(const short8*)&A[(wm * 32 + m * 16 + (lane & 15)) * 72 + ks * 32 + (lane >> 4) * 8];
#pragma unroll
            for (int n = 0; n < 4; ++n)
                b[n] = *(const short8*)&BT[(wn * 64 + n * 16 + (lane & 15)) * 72 + ks * 32 + (lane >> 4) * 8];
#pragma unroll
            for (int m = 0; m < 2; ++m)
#pragma unroll
                for (int n = 0; n < 4; ++n)
                    acc[m][n] = __builtin_amdgcn_mfma_f32_16x16x32_bf16(a[m], b[n], acc[m][n], 0, 0, 0);
        }
        __syncthreads();
    }
#pragma unroll
    for (int m = 0; m < 2; ++m)
#pragma unroll
    for (int n = 0; n < 4; ++n) {
        int col = wn * 64 + n * 16 + (lane & 15);
        float bias = bsi2[col];
#pragma unroll
        for (int r = 0; r < 4; ++r) {
            int row = rbase + wm * 32 + m * 16 + (lane >> 4) * 4 + r;
            spb[row * 128 + col] = f2b(acc[m][n][r] + bias);
        }
    }
}

__global__ __launch_bounds__(1024) void k_scan(
    const int* __restrict__ bcnt, int* __restrict__ chunkoff,
    int* __restrict__ pad) {
    __shared__ int sc[1024];
    __shared__ int tot[8];
    __shared__ int spo[8];
    const int t = threadIdx.x;
    for (int g = 0; g < 6; ++g) {
        int v = bcnt[t * 6 + g];
        sc[t] = v;
        __syncthreads();
        for (int s = 1; s < 1024; s <<= 1) {
            int u = (t >= s) ? sc[t - s] : 0;
            __syncthreads();
            sc[t] += u;
            __syncthreads();
        }
        if (t == 1023) tot[g] = sc[t];
        chunkoff[t * 6 + g] = sc[t] - v;
        __syncthreads();
    }
    if (t == 0) {
        int off = 0;
        for (int g = 0; g < 6; ++g) {
            spo[g] = off; pad[g] = off; pad[8 + g] = tot[g];
            off += ((tot[g] + 63) >> 6) << 6;
        }
        spo[6] = off; pad[6] = off;
    }
    __syncthreads();
    for (int g = 0; g < 6; ++g) chunkoff[t * 6 + g] += spo[g];
}

__global__ __launch_bounds__(256) void k_scatter(
    const int* __restrict__ cmd, const int* __restrict__ chunkoff,
    int* __restrict__ perm) {
    const int lane = threadIdx.x & 63, w = threadIdx.x >> 6;
    const int chunk = blockIdx.x * 4 + w;
    const int idx = chunk * 64 + lane;
    const int c = cmd[idx] - 1;
#pragma unroll
    for (int g = 0; g < 6; ++g) {
        unsigned long long m = __ballot(c == g);
        if (c == g) {
            int pos = chunkoff[chunk * 6 + g] + (int)__popcll(m & ((1ull << lane) - 1ull));
            perm[pos] = idx;
        }
    }
}

// -------- fused 3-layer head: A via gll-dbuf, B global->reg in-place --------
__global__ __launch_bounds__(256, 3) void k_head(
    const float* __restrict__ emb, const bhalf* __restrict__ spb,
    const bhalf* __restrict__ Wso1T, const float* __restrict__ bso1,
    const bhalf* __restrict__ Wso2T, const float* __restrict__ bso2,
    const float* __restrict__ Wso3, const float* __restrict__ bso3,
    const bhalf* __restrict__ Wb1T, const float* __restrict__ bb1,
    const bhalf* __restrict__ Wb2T, const float* __restrict__ bb2,
    const float* __restrict__ Wb3, const float* __restrict__ bb3,
    const int* __restrict__ pad, const int* __restrict__ perm,
    float* __restrict__ out) {
    __shared__ __align__(16) char L[49152];
    char* const SA0 = L;           // 2 x 8192: f32 A dbuf (sp bf16 in low 4K)
    char* const Yb  = L + 16384;   // 32KB Y [64][256] bf16 swizzled
    const int t = threadIdx.x, lane = t & 63, wid = t >> 6;
    const bool isB = blockIdx.x < NBRB;
    int tstart, DOUT, gcnt, gbase;
    const bhalf *W1T, *W2T; const float *b1, *b2, *W3, *b3;
    if (isB) {
        tstart = blockIdx.x * 64;
        if (tstart >= pad[6]) return;
        int g = 0;
        while (pad[g + 1] <= tstart) ++g;
        gbase = pad[g]; gcnt = pad[8 + g];
        W1T = Wb1T + (size_t)g * (256 * 640); b1 = bb1 + g * 256;
        W2T = Wb2T + (size_t)g * (256 * 256); b2 = bb2 + g * 256;
        W3  = Wb3  + (size_t)g * (256 * 3);   b3 = bb3 + g * 3;
        DOUT = 3;
    } else {
        tstart = (blockIdx.x - NBRB) * 64;
        gbase = 0; gcnt = NB;
        W1T = Wso1T; b1 = bso1; W2T = Wso2T; b2 = bso2; W3 = Wso3; b3 = bso3;
        DOUT = 1;
    }

    // A staging source maps (gll: linear dest, inverse-swizzled source)
    const int rowA0 = t >> 3, rowA1 = rowA0 + 32, rowS = t >> 2;
    int ra0, ra1, raS;
    if (isB) {
        int p0 = tstart + rowA0, p1 = tstart + rowA1, pS = tstart + rowS;
        ra0 = ((p0 - gbase) < gcnt) ? perm[p0] : 0;
        ra1 = ((p1 - gbase) < gcnt) ? perm[p1] : 0;
        raS = ((pS - gbase) < gcnt) ? perm[pS] : 0;
    } else {
        ra0 = tstart + rowA0; ra1 = tstart + rowA1; raS = tstart + rowS;
    }
    const int lcA0 = ((t & 7) * 16) ^ ((rowA0 & 7) << 4);
    const int lcA1 = ((t & 7) * 16) ^ ((rowA1 & 7) << 4);
    const int lcS  = ((t & 3) * 16) ^ (((rowS >> 1) & 3) << 4);
    const char* embp0 = (const char*)(emb + (size_t)ra0 * 512);
    const char* embp1 = (const char*)(emb + (size_t)ra1 * 512);
    const char* spbp  = (const char*)(spb + (size_t)raS * 128);
    const int dstA = t * 16;

#define ST_A(KN, BUF) do { int kn_ = (KN); char* d_ = SA0 + (BUF) * 8192 + dstA; \
        if (kn_ < 16) {                                                           \
            gll16(embp0 + kn_ * 128 + lcA0, d_);                                  \
            gll16(embp1 + kn_ * 128 + lcA1, d_ + 4096);                           \
        } else {                                                                  \
            gll16(spbp + (kn_ - 16) * 64 + lcS, d_);                              \
            gll16(spbp + (kn_ - 16) * 64 + lcS, d_ + 4096);                       \
        } } while (0)

    const int arow = lane & 15, koff = (lane >> 4) * 16;
    const int kb = (lane >> 4) * 16;
    const int col0 = wid * 64 + arow;
    // B row pointers: W1 row stride 1280B, W2 row stride 512B
    const char* bp0 = (const char*)W1T + (size_t)(col0 +  0) * 1280 + kb;
    const char* bp1 = (const char*)W1T + (size_t)(col0 + 16) * 1280 + kb;
    const char* bp2 = (const char*)W1T + (size_t)(col0 + 32) * 1280 + kb;
    const char* bp3 = (const char*)W1T + (size_t)(col0 + 48) * 1280 + kb;
    const char* cp0 = (const char*)W2T + (size_t)(col0 +  0) * 512 + kb;
    const char* cp1 = (const char*)W2T + (size_t)(col0 + 16) * 512 + kb;
    const char* cp2 = (const char*)W2T + (size_t)(col0 + 32) * 512 + kb;
    const char* cp3 = (const char*)W2T + (size_t)(col0 + 48) * 512 + kb;

    float bi1[4], bi2[4];
#pragma unroll
    for (int n = 0; n < 4; ++n) {
        bi1[n] = b1[col0 + n * 16];
        bi2[n] = b2[col0 + n * 16];
    }

    f32x4 acc[4][4];
#pragma unroll
    for (int m = 0; m < 4; ++m)
#pragma unroll
        for (int n = 0; n < 4; ++n)
#pragma unroll
            for (int r = 0; r < 4; ++r) acc[m][n][r] = 0.f;

    // ---------------- layer 1: K=640, 20 sections ----------------
    short8 bc0 = *(const short8*)bp0;
    short8 bc1 = *(const short8*)bp1;
    short8 bc2 = *(const short8*)bp2;
    short8 bc3 = *(const short8*)bp3;
    ST_A(0, 0);
    for (int kc = 0; kc < 20; ++kc) {
        const int buf = kc & 1;
        // vmcnt is FIFO: the wait must force THIS section's A-glls complete.
        // kc==0: newer ops after gll0 are only gll1(2) -> wvm2 (r11 bug fix).
        // 1<=kc<19: newer = 4 B-reloads (prev compute) + 2 gll -> wvm6.
        // kc==19: newer = 4 B-reloads -> wvm4.
        if (kc == 0)      { ST_A(1, 1); wvm2(); }
        else if (kc < 19) { ST_A(kc + 1, buf ^ 1); wvm6(); }
        else              { wvm4(); }
        __builtin_amdgcn_s_barrier();
        const char* SAc = SA0 + buf * 8192;
        short8 a[4];
        if (kc < 16) {
#pragma unroll
            for (int m = 0; m < 4; ++m) {
                int row = m * 16 + arow;
                int sw = (row & 7) << 4;
                int c0 = (lane >> 4) * 32;
                float4 f0 = *(const float4*)(SAc + row * 128 + (c0 ^ sw));
                float4 f1 = *(const float4*)(SAc + row * 128 + ((c0 + 16) ^ sw));
                a[m][0] = (short)f2b(f0.x); a[m][1] = (short)f2b(f0.y);
                a[m][2] = (short)f2b(f0.z); a[m][3] = (short)f2b(f0.w);
                a[m][4] = (short)f2b(f1.x); a[m][5] = (short)f2b(f1.y);
                a[m][6] = (short)f2b(f1.z); a[m][7] = (short)f2b(f1.w);
            }
        } else {
#pragma unroll
            for (int m = 0; m < 4; ++m)
                a[m] = *(const short8*)(SAc + sadr(m * 16 + arow, koff));
        }
        // n-major MFMA; reload each B frag in place right after last use.
        // next source: kc<19 -> W1 sec kc+1; kc==19 -> W2 sec 0 (hides under epi-1)
        {
            const char* n0p = (kc < 19) ? bp0 + (kc + 1) * 64 : cp0;
            const char* n1p = (kc < 19) ? bp1 + (kc + 1) * 64 : cp1;
            const char* n2p = (kc < 19) ? bp2 + (kc + 1) * 64 : cp2;
            const char* n3p = (kc < 19) ? bp3 + (kc + 1) * 64 : cp3;
#pragma unroll
            for (int m = 0; m < 4; ++m)
                acc[m][0] = __builtin_amdgcn_mfma_f32_16x16x32_bf16(a[m], bc0, acc[m][0], 0, 0, 0);
            bc0 = *(const short8*)n0p;
#pragma unroll
            for (int m = 0; m < 4; ++m)
                acc[m][1] = __builtin_amdgcn_mfma_f32_16x16x32_bf16(a[m], bc1, acc[m][1], 0, 0, 0);
            bc1 = *(const short8*)n1p;
#pragma unroll
            for (int m = 0; m < 4; ++m)
                acc[m][2] = __builtin_amdgcn_mfma_f32_16x16x32_bf16(a[m], bc2, acc[m][2], 0, 0, 0);
            bc2 = *(const short8*)n2p;
#pragma unroll
            for (int m = 0; m < 4; ++m)
                acc[m][3] = __builtin_amdgcn_mfma_f32_16x16x32_bf16(a[m], bc3, acc[m][3], 0, 0, 0);
            bc3 = *(const short8*)n3p;
        }
        __builtin_amdgcn_s_barrier();
    }
    // epi 1: bias+relu -> Y (L2's bc frags already in flight)
#pragma unroll
    for (int m = 0; m < 4; ++m)
#pragma unroll
    for (int n = 0; n < 4; ++n) {
        int col = wid * 64 + n * 16 + arow;
#pragma unroll
        for (int r = 0; r < 4; ++r) {
            int row = m * 16 + (lane >> 4) * 4 + r;
            *(bhalf*)(Yb + yadr(row, 2 * col)) = f2b(fmaxf(acc[m][n][r] + bi1[n], 0.f));
            acc[m][n][r] = 0.f;
        }
    }
    wlgkm0();
    __builtin_amdgcn_s_barrier();
    // ---------------- layer 2: K=256, 8 sections, no staging/barriers -------
    for (int kc = 0; kc < 8; ++kc) {
        short8 a[4];
#pragma unroll
        for (int m = 0; m < 4; ++m)
            a[m] = *(const short8*)(Yb + yadr(m * 16 + arow, kc * 64 + koff));
#pragma unroll
        for (int m = 0; m < 4; ++m)
            acc[m][0] = __builtin_amdgcn_mfma_f32_16x16x32_bf16(a[m], bc0, acc[m][0], 0, 0, 0);
        if (kc < 7) bc0 = *(const short8*)(cp0 + (kc + 1) * 64);
#pragma unroll
        for (int m = 0; m < 4; ++m)
            acc[m][1] = __builtin_amdgcn_mfma_f32_16x16x32_bf16(a[m], bc1, acc[m][1], 0, 0, 0);
        if (kc < 7) bc1 = *(const short8*)(cp1 + (kc + 1) * 64);
#pragma unroll
        for (int m = 0; m < 4; ++m)
            acc[m][2] = __builtin_amdgcn_mfma_f32_16x16x32_bf16(a[m], bc2, acc[m][2], 0, 0, 0);
        if (kc < 7) bc2 = *(const short8*)(cp2 + (kc + 1) * 64);
#pragma unroll
        for (int m = 0; m < 4; ++m)
            acc[m][3] = __builtin_amdgcn_mfma_f32_16x16x32_bf16(a[m], bc3, acc[m][3], 0, 0, 0);
        if (kc < 7) bc3 = *(const short8*)(cp3 + (kc + 1) * 64);
    }
    __builtin_amdgcn_s_barrier();   // all waves done reading Y
    // epi 2: bias+relu -> Y
#pragma unroll
    for (int m = 0; m < 4; ++m)
#pragma unroll
    for (int n = 0; n < 4; ++n) {
        int col = wid * 64 + n * 16 + arow;
#pragma unroll
        for (int r = 0; r < 4; ++r) {
            int row = m * 16 + (lane >> 4) * 4 + r;
            *(bhalf*)(Yb + yadr(row, 2 * col)) = f2b(fmaxf(acc[m][n][r] + bi2[n], 0.f));
        }
    }
    wlgkm0();
    __builtin_amdgcn_s_barrier();
    // ---------------- layer 3: MFMA, wave w owns rows w*16..w*16+15 ---------
    f32x4 z;
#pragma unroll
    for (int r = 0; r < 4; ++r) z[r] = 0.f;
    const int col3 = arow;
    for (int kc = 0; kc < 8; ++kc) {
        short8 a3 = *(const short8*)(Yb + yadr(wid * 16 + arow, kc * 64 + koff));
        short8 bw;
#pragma unroll
        for (int j = 0; j < 8; ++j) bw[j] = 0;
        if (col3 < DOUT) {
            int kbq = kc * 32 + (lane >> 4) * 8;
#pragma unroll
            for (int j = 0; j < 8; ++j)
                bw[j] = (short)f2b(W3[(kbq + j) * DOUT + col3]);
        }
        z = __builtin_amdgcn_mfma_f32_16x16x32_bf16(a3, bw, z, 0, 0, 0);
    }
    if (col3 < DOUT) {
        float bias = b3[col3];
#pragma unroll
        for (int rr = 0; rr < 4; ++rr) {
            int r = wid * 16 + (lane >> 4) * 4 + rr;
            int p2 = tstart + r;
            if ((p2 - gbase) < gcnt) {
                float v = z[rr] + bias;
                if (isB) {
                    int ro = perm[p2];
                    out[(size_t)ro * 3 + col3] = 1.f / (1.f + __expf(-v));
                } else {
                    out[(size_t)NB * 3 + p2] = v;
                }
            }
        }
    }
#undef ST_A
}

extern "C" void kernel_launch(void* const* d_in, const int* in_sizes, int n_in,
                              void* d_out, int out_size, void* d_ws, size_t ws_size,
                              hipStream_t stream) {
    (void)in_sizes; (void)n_in; (void)out_size; (void)ws_size;
    const float* emb   = (const float*)d_in[0];
    const float* speed = (const float*)d_in[1];
    const int*   cmd   = (const int*)d_in[2];
    const float* Wsi1  = (const float*)d_in[3];
    const float* bsi1  = (const float*)d_in[4];
    const float* Wsi2  = (const float*)d_in[5];
    const float* bsi2  = (const float*)d_in[6];
    const float* Wso1  = (const float*)d_in[7];
    const float* bso1  = (const float*)d_in[8];
    const float* Wso2  = (const float*)d_in[9];
    const float* bso2  = (const float*)d_in[10];
    const float* Wso3  = (const float*)d_in[11];
    const float* bso3  = (const float*)d_in[12];
    const float* Wb1   = (const float*)d_in[13];
    const float* bb1   = (const float*)d_in[14];
    const float* Wb2   = (const float*)d_in[15];
    const float* bb2   = (const float*)d_in[16];
    const float* Wb3   = (const float*)d_in[17];
    const float* bb3   = (const float*)d_in[18];
    float* out = (float*)d_out;

    char* ws = (char*)d_ws;
    bhalf* spb      = (bhalf*)(ws);
    int*   perm     = (int*)(ws + 16777216);
    int*   bcnt     = (int*)(ws + 17040896);
    int*   chunkoff = (int*)(ws + 17065472);
    int*   pad      = (int*)(ws + 17090048);
    bhalf* Wsi2T    = (bhalf*)(ws + 17090304);
    bhalf* Wso1T    = (bhalf*)(ws + 17155840);
    bhalf* Wso2T    = (bhalf*)(ws + 17483520);
    bhalf* Wb1T     = (bhalf*)(ws + 17614592);
    bhalf* Wb2T     = (bhalf*)(ws + 19580672);

    k_wprep<<<400, 256, 0, stream>>>(Wsi2, Wso1, Wso2, Wb1, Wb2,
                                     Wsi2T, Wso1T, Wso2T, Wb1T, Wb2T);
    k_prep<<<NB / 64, 256, 0, stream>>>(speed, Wsi1, bsi1, Wsi2T, bsi2, cmd,
                                        spb, bcnt);
    k_scan<<<1, 1024, 0, stream>>>(bcnt, chunkoff, pad);
    k_scatter<<<NB / 256, 256, 0, stream>>>(cmd, chunkoff, perm);
    k_head<<<NBRB + NB / 64, 256, 0, stream>>>(emb, spb,
                                               Wso1T, bso1, Wso2T, bso2, Wso3, bso3,
                                               Wb1T, bb1, Wb2T, bb2, Wb3, bb3,
                                               pad, perm, out);
}

// Round 13
// 171.457 us; speedup vs baseline: 2.1998x; 1.0858x over previous
//
#include <hip/hip_runtime.h>
#include <hip/hip_bf16.h>

// CILRS head, MI355X round 13.
// Model from r6/r8/r12: time = max(total gll bytes / 9.8TB/s, serialized
// pipe sum under barrier lockstep). Only lever cutting TOTAL staged bytes:
// stage A once for BOTH heads (r8-k1 proven: N=512, acc[4][8], wvm10,
// VGPR 112 no-spill). This round fuses r8-k1's L1 verbatim with in-block
// L2+L3 per head (r12's proven barrier-free reg-B loops; Y in 64KB LDS
// overlay -> no Yg roundtrip, no k2, emb read once). Grid 1030 -> 2.01
// generations at 2 blocks/CU (r8's 3rd-gen tail removed).
// ws layout (bytes):
//   0        spb      : B*128 bf16 sp-latent (16,777,216)
//   16777216 perm     : (B+384) int32
//   17040896 bcnt     : [1024][6] int
//   17065472 chunkoff : [1024][6] int
//   17090048 pad      : pad[0..6]=offsets, pad[8+g]=totals
//   17090304 Wsi2T / 17155840 Wso1T / 17483520 Wso2T / 17614592 Wb1T /
//   19580672 Wb2T  (end 20,367,104)

#define NB 65536
#define NGRID 1030

typedef __attribute__((ext_vector_type(8))) short short8;
typedef __attribute__((ext_vector_type(4))) float f32x4;
typedef unsigned short bhalf;
typedef unsigned int u32;

__device__ __forceinline__ bhalf f2b(float x) {
    __hip_bfloat16 h = __float2bfloat16(x);
    return *reinterpret_cast<bhalf*>(&h);
}
__device__ __forceinline__ void gll16(const void* g, void* l) {
    __builtin_amdgcn_global_load_lds(
        (const __attribute__((address_space(1))) u32*)g,
        (__attribute__((address_space(3))) u32*)l, 16, 0, 0);
}
// 64B-row bf16 tiles: phys = row*64 + (cb ^ (((row>>1)&3)<<4))
__device__ __forceinline__ int sadr(int row, int cb) {
    return row * 64 + (cb ^ (((row >> 1) & 3) << 4));
}
// 1024B-row tile (Y overlay, 512 cols bf16)
__device__ __forceinline__ int yadr2(int row, int cb) {
    return row * 1024 + (cb ^ ((row & 7) << 4));
}
__device__ __forceinline__ void wvm10() { asm volatile("s_waitcnt vmcnt(10)" ::: "memory"); }
__device__ __forceinline__ void wvm0()  { asm volatile("s_waitcnt vmcnt(0)"  ::: "memory"); }
__device__ __forceinline__ void wlgkm0(){ asm volatile("s_waitcnt lgkmcnt(0)" ::: "memory"); }

// -------- weight transpose, 64x64 LDS tiles --------
__global__ __launch_bounds__(256) void k_wprep(
    const float* __restrict__ Wsi2, const float* __restrict__ Wso1,
    const float* __restrict__ Wso2, const float* __restrict__ Wb1,
    const float* __restrict__ Wb2,
    bhalf* __restrict__ Wsi2T, bhalf* __restrict__ Wso1T,
    bhalf* __restrict__ Wso2T, bhalf* __restrict__ Wb1T,
    bhalf* __restrict__ Wb2T) {
    __shared__ float T[64][65];
    const int id = blockIdx.x, t = threadIdx.x;
    const float* src; bhalf* dst; int K, N, tk, tn, b;
    if (id < 8)        { src = Wsi2; dst = Wsi2T; K = 256; N = 128; b = 0; int tl = id;      tk = tl / 2; tn = tl % 2; }
    else if (id < 48)  { src = Wso1; dst = Wso1T; K = 640; N = 256; b = 0; int tl = id - 8;  tk = tl / 4; tn = tl % 4; }
    else if (id < 64)  { src = Wso2; dst = Wso2T; K = 256; N = 256; b = 0; int tl = id - 48; tk = tl / 4; tn = tl % 4; }
    else if (id < 304) { src = Wb1;  dst = Wb1T;  K = 640; N = 256; int li = id - 64;  b = li / 40; int tl = li % 40; tk = tl / 4; tn = tl % 4; }
    else               { src = Wb2;  dst = Wb2T;  K = 256; N = 256; int li = id - 304; b = li / 16; int tl = li % 16; tk = tl / 4; tn = tl % 4; }
    const int k0 = tk * 64, n0 = tn * 64;
    src += (size_t)b * K * N; dst += (size_t)b * N * K;
    const int c = t & 63, r0 = t >> 6;
#pragma unroll
    for (int j = 0; j < 16; ++j) {
        int r = r0 + j * 4;
        T[r][c] = src[(size_t)(k0 + r) * N + n0 + c];
    }
    __syncthreads();
#pragma unroll
    for (int j = 0; j < 16; ++j) {
        int r = r0 + j * 4;
        dst[(size_t)(n0 + r) * K + k0 + c] = f2b(T[c][r]);
    }
}

// speed-latent + per-chunk command counts (NO atomics)
__global__ __launch_bounds__(256) void k_prep(
    const float* __restrict__ speed, const float* __restrict__ Wsi1,
    const float* __restrict__ bsi1, const bhalf* __restrict__ Wsi2T,
    const float* __restrict__ bsi2, const int* __restrict__ cmd,
    bhalf* __restrict__ spb, int* __restrict__ bcnt) {
    __shared__ bhalf A[64 * 72];
    __shared__ bhalf BT[128 * 72];
    const int t = threadIdx.x, lane = t & 63, wid = t >> 6;
    const int rbase = blockIdx.x * 64;
    if (wid == 0) {
        int c = cmd[rbase + lane] - 1;
        int v = 0;
#pragma unroll
        for (int g = 0; g < 6; ++g) {
            unsigned long long m = __ballot(c == g);
            if (lane == g) v = (int)__popcll(m);
        }
        if (lane < 6) bcnt[blockIdx.x * 6 + lane] = v;
    }
    const int wm = wid >> 1, wn = wid & 1;
    f32x4 acc[2][4];
    for (int m = 0; m < 2; ++m) for (int n = 0; n < 4; ++n)
        for (int r = 0; r < 4; ++r) acc[m][n][r] = 0.f;
    const int ar = t >> 2, kp = (t & 3) * 16;
    const float s = speed[rbase + ar];
    for (int kc = 0; kc < 4; ++kc) {
        short8 w0, w1;
#pragma unroll
        for (int j = 0; j < 8; ++j) {
            int k = kc * 64 + kp + j;
            w0[j] = (short)f2b(fmaxf(fmaf(s, Wsi1[k], bsi1[k]), 0.f));
            w1[j] = (short)f2b(fmaxf(fmaf(s, Wsi1[k + 8], bsi1[k + 8]), 0.f));
        }
        *(short8*)&A[ar * 72 + kp] = w0;
        *(short8*)&A[ar * 72 + kp + 8] = w1;
#pragma unroll
        for (int j = 0; j < 4; ++j) {
            int ch = t + j * 256;
            int n2 = ch >> 3, ko = (ch & 7) * 8;
            *(short8*)&BT[n2 * 72 + ko] =
                *(const short8*)(Wsi2T + n2 * 256 + kc * 64 + ko);
        }
        __syncthreads();
#pragma unroll
        for (int ks = 0; ks < 2; ++ks) {
            short8 a[2], b[4];
#pragma unroll
            for (int m = 0; m < 2; ++m)
                a[m] = *(const short8*)&A[(wm * 32 + m * 16 + (lane & 15)) * 72 + ks * 32 + (lane >> 4) * 8];
#pragma unroll
            for (int n = 0; n < 4; ++n)
                b[n] = *(const short8*)&BT[(wn * 64 + n * 16 + (lane & 15)) * 72 + ks * 32 + (lane >> 4) * 8];
#pragma unroll
            for (int m = 0; m < 2; ++m)
#pragma unroll
                for (int n = 0; n < 4; ++n)
                    acc[m][n] = __builtin_amdgcn_mfma_f32_16x16x32_bf16(a[m], b[n], acc[m][n], 0, 0, 0);
        }
        __syncthreads();
    }
#pragma unroll
    for (int m = 0; m < 2; ++m)
#pragma unroll
    for (int n = 0; n < 4; ++n) {
        int col = wn * 64 + n * 16 + (lane & 15);
        float bias = bsi2[col];
#pragma unroll
        for (int r = 0; r < 4; ++r) {
            int row = rbase + wm * 32 + m * 16 + (lane >> 4) * 4 + r;
            spb[row * 128 + col] = f2b(acc[m][n][r] + bias);
        }
    }
}

__global__ __launch_bounds__(1024) void k_scan(
    const int* __restrict__ bcnt, int* __restrict__ chunkoff,
    int* __restrict__ pad) {
    __shared__ int sc[1024];
    __shared__ int tot[8];
    __shared__ int spo[8];
    const int t = threadIdx.x;
    for (int g = 0; g < 6; ++g) {
        int v = bcnt[t * 6 + g];
        sc[t] = v;
        __syncthreads();
        for (int s = 1; s < 1024; s <<= 1) {
            int u = (t >= s) ? sc[t - s] : 0;
            __syncthreads();
            sc[t] += u;
            __syncthreads();
        }
        if (t == 1023) tot[g] = sc[t];
        chunkoff[t * 6 + g] = sc[t] - v;
        __syncthreads();
    }
    if (t == 0) {
        int off = 0;
        for (int g = 0; g < 6; ++g) {
            spo[g] = off; pad[g] = off; pad[8 + g] = tot[g];
            off += ((tot[g] + 63) >> 6) << 6;
        }
        spo[6] = off; pad[6] = off;
    }
    __syncthreads();
    for (int g = 0; g < 6; ++g) chunkoff[t * 6 + g] += spo[g];
}

__global__ __launch_bounds__(256) void k_scatter(
    const int* __restrict__ cmd, const int* __restrict__ chunkoff,
    int* __restrict__ perm) {
    const int lane = threadIdx.x & 63, w = threadIdx.x >> 6;
    const int chunk = blockIdx.x * 4 + w;
    const int idx = chunk * 64 + lane;
    const int c = cmd[idx] - 1;
#pragma unroll
    for (int g = 0; g < 6; ++g) {
        unsigned long long m = __ballot(c == g);
        if (c == g) {
            int pos = chunkoff[chunk * 6 + g] + (int)__popcll(m & ((1ull << lane) - 1ull));
            perm[pos] = idx;
        }
    }
}

// ===== fused head: L1 both heads (r8-k1 verbatim), then L2+L3 per head ======
__global__ __launch_bounds__(256, 2) void k_head(
    const float* __restrict__ emb, const bhalf* __restrict__ spb,
    const bhalf* __restrict__ Wso1T, const float* __restrict__ bso1,
    const bhalf* __restrict__ Wso2T, const float* __restrict__ bso2,
    const float* __restrict__ Wso3, const float* __restrict__ bso3,
    const bhalf* __restrict__ Wb1T, const float* __restrict__ bb1,
    const bhalf* __restrict__ Wb2T, const float* __restrict__ bb2,
    const float* __restrict__ Wb3, const float* __restrict__ bb3,
    const int* __restrict__ pad, const int* __restrict__ perm,
    float* __restrict__ out) {
    __shared__ __align__(16) char L[81920];
    char* const SA0 = L;            // 2 x 8192 A dbuf
    char* const SB0 = L + 16384;    // 2 x 32768 B dbuf (branch 16K + speed 16K)
    char* const Yb  = L;            // after L1: Y [64][512] bf16 overlay
    const int t = threadIdx.x, lane = t & 63, wid = t >> 6;
    const int tstart = blockIdx.x * 64;
    if (tstart >= pad[6]) return;
    int g = 0;
    while (pad[g + 1] <= tstart) ++g;
    const int gbase = pad[g], gcnt = pad[8 + g];
    const bhalf* W1b = Wb1T + (size_t)g * (256 * 640);
    const bhalf* W2b = Wb2T + (size_t)g * (256 * 256);
    const float* W3b = Wb3 + (size_t)g * (256 * 3);
    const float* b3b = bb3 + g * 3;

    const int rowA0 = t >> 3, rowA1 = rowA0 + 32, rowS = t >> 2;
    int p0 = tstart + rowA0, p1 = tstart + rowA1, pS = tstart + rowS;
    const int ra0 = ((p0 - gbase) < gcnt) ? perm[p0] : 0;
    const int ra1 = ((p1 - gbase) < gcnt) ? perm[p1] : 0;
    const int raS = ((pS - gbase) < gcnt) ? perm[pS] : 0;
    const int lcA0 = ((t & 7) * 16) ^ ((rowA0 & 7) << 4);
    const int lcA1 = ((t & 7) * 16) ^ ((rowA1 & 7) << 4);
    const int lcS  = ((t & 3) * 16) ^ (((rowS >> 1) & 3) << 4);
    const char* embp0 = (const char*)(emb + (size_t)ra0 * 512);
    const char* embp1 = (const char*)(emb + (size_t)ra1 * 512);
    const char* spbp  = (const char*)(spb + (size_t)raS * 128);
    const int dstA = t * 16;
    const int rB = t >> 2, cB = (t & 3) * 16;

#define ST_A(KN, BUF) do { int kn_ = (KN); char* d_ = SA0 + (BUF) * 8192 + dstA; \
        if (kn_ < 16) {                                                           \
            gll16(embp0 + kn_ * 128 + lcA0, d_);                                  \
            gll16(embp1 + kn_ * 128 + lcA1, d_ + 4096);                           \
        } else {                                                                  \
            gll16(spbp + (kn_ - 16) * 64 + lcS, d_);                              \
            gll16(spbp + (kn_ - 16) * 64 + lcS, d_ + 4096);                       \
        } } while (0)
#define ST_B(KN, BUF) do {                                                        \
        _Pragma("unroll")                                                         \
        for (int j_ = 0; j_ < 4; ++j_) {                                          \
            int row_ = rB + j_ * 64;                                              \
            int p_ = row_ * 64 + cB;                                              \
            int lc_ = cB ^ (((row_ >> 1) & 3) << 4);                              \
            gll16((const char*)W1b + (size_t)row_ * 1280 + (KN) * 64 + lc_,       \
                  SB0 + (BUF) * 32768 + p_);                                      \
            gll16((const char*)Wso1T + (size_t)row_ * 1280 + (KN) * 64 + lc_,     \
                  SB0 + (BUF) * 32768 + 16384 + p_);                              \
        } } while (0)

    const int arow = lane & 15, koff = (lane >> 4) * 16;
    const int col0 = wid * 64 + arow;
    float bi1[8], bi2b[4], bi2s[4];
#pragma unroll
    for (int n = 0; n < 4; ++n) {
        bi1[n]     = bb1[g * 256 + col0 + n * 16];
        bi1[n + 4] = bso1[col0 + n * 16];
        bi2b[n]    = bb2[g * 256 + col0 + n * 16];
        bi2s[n]    = bso2[col0 + n * 16];
    }

    f32x4 acc[4][8];
#pragma unroll
    for (int m = 0; m < 4; ++m)
#pragma unroll
        for (int n = 0; n < 8; ++n)
#pragma unroll
            for (int r = 0; r < 4; ++r) acc[m][n][r] = 0.f;

    // ---------------- layer 1: K=640, 20 sections (r8-k1 schedule) ----------
    ST_A(0, 0); ST_B(0, 0);                  // 10 outstanding
    for (int kc = 0; kc < 20; ++kc) {
        const int buf = kc & 1;
        if (kc < 19) { ST_A(kc + 1, buf ^ 1); ST_B(kc + 1, buf ^ 1); wvm10(); }
        else         { wvm0(); }
        __builtin_amdgcn_s_barrier();
        const char* SAc = SA0 + buf * 8192;
        const char* SBc = SB0 + buf * 32768;
        short8 a[4], b[8];
#pragma unroll
        for (int n = 0; n < 4; ++n) {
            b[n]     = *(const short8*)(SBc + sadr(wid * 64 + n * 16 + arow, koff));
            b[n + 4] = *(const short8*)(SBc + 16384 + sadr(wid * 64 + n * 16 + arow, koff));
        }
        if (kc < 16) {
#pragma unroll
            for (int m = 0; m < 4; ++m) {
                int row = m * 16 + arow;
                int sw = (row & 7) << 4;
                int c0 = (lane >> 4) * 32;
                float4 f0 = *(const float4*)(SAc + row * 128 + (c0 ^ sw));
                float4 f1 = *(const float4*)(SAc + row * 128 + ((c0 + 16) ^ sw));
                a[m][0] = (short)f2b(f0.x); a[m][1] = (short)f2b(f0.y);
                a[m][2] = (short)f2b(f0.z); a[m][3] = (short)f2b(f0.w);
                a[m][4] = (short)f2b(f1.x); a[m][5] = (short)f2b(f1.y);
                a[m][6] = (short)f2b(f1.z); a[m][7] = (short)f2b(f1.w);
            }
        } else {
#pragma unroll
            for (int m = 0; m < 4; ++m)
                a[m] = *(const short8*)(SAc + sadr(m * 16 + arow, koff));
        }
#pragma unroll
        for (int m = 0; m < 4; ++m)
#pragma unroll
            for (int n = 0; n < 8; ++n)
                acc[m][n] = __builtin_amdgcn_mfma_f32_16x16x32_bf16(a[m], b[n], acc[m][n], 0, 0, 0);
        __builtin_amdgcn_s_barrier();
    }
    // issue branch-L2 sec-0 B frags early (hide L2 latency under epi-1)
    const int kb = koff;
    const char* cpb0 = (const char*)W2b + (size_t)(col0 +  0) * 512 + kb;
    const char* cpb1 = (const char*)W2b + (size_t)(col0 + 16) * 512 + kb;
    const char* cpb2 = (const char*)W2b + (size_t)(col0 + 32) * 512 + kb;
    const char* cpb3 = (const char*)W2b + (size_t)(col0 + 48) * 512 + kb;
    const char* cps0 = (const char*)Wso2T + (size_t)(col0 +  0) * 512 + kb;
    const char* cps1 = (const char*)Wso2T + (size_t)(col0 + 16) * 512 + kb;
    const char* cps2 = (const char*)Wso2T + (size_t)(col0 + 32) * 512 + kb;
    const char* cps3 = (const char*)Wso2T + (size_t)(col0 + 48) * 512 + kb;
    short8 bc0 = *(const short8*)cpb0;
    short8 bc1 = *(const short8*)cpb1;
    short8 bc2 = *(const short8*)cpb2;
    short8 bc3 = *(const short8*)cpb3;
    // epi-1: bias+relu -> Y overlay [0,65536)
#pragma unroll
    for (int m = 0; m < 4; ++m)
#pragma unroll
    for (int n = 0; n < 8; ++n) {
        int col = (n < 4) ? (wid * 64 + n * 16 + arow)
                          : (256 + wid * 64 + (n - 4) * 16 + arow);
#pragma unroll
        for (int r = 0; r < 4; ++r) {
            int row = m * 16 + (lane >> 4) * 4 + r;
            *(bhalf*)(Yb + yadr2(row, 2 * col)) = f2b(fmaxf(acc[m][n][r] + bi1[n], 0.f));
            acc[m][n][r] = 0.f;
        }
    }
    wlgkm0();
    __builtin_amdgcn_s_barrier();
    // ---------------- L2 branch: K=256, 8 sections, no barriers -------------
    for (int kc = 0; kc < 8; ++kc) {
        short8 a[4];
#pragma unroll
        for (int m = 0; m < 4; ++m)
            a[m] = *(const short8*)(Yb + yadr2(m * 16 + arow, kc * 64 + koff));
#pragma unroll
        for (int m = 0; m < 4; ++m)
            acc[m][0] = __builtin_amdgcn_mfma_f32_16x16x32_bf16(a[m], bc0, acc[m][0], 0, 0, 0);
        if (kc < 7) bc0 = *(const short8*)(cpb0 + (kc + 1) * 64); else bc0 = *(const short8*)cps0;
#pragma unroll
        for (int m = 0; m < 4; ++m)
            acc[m][1] = __builtin_amdgcn_mfma_f32_16x16x32_bf16(a[m], bc1, acc[m][1], 0, 0, 0);
        if (kc < 7) bc1 = *(const short8*)(cpb1 + (kc + 1) * 64); else bc1 = *(const short8*)cps1;
#pragma unroll
        for (int m = 0; m < 4; ++m)
            acc[m][2] = __builtin_amdgcn_mfma_f32_16x16x32_bf16(a[m], bc2, acc[m][2], 0, 0, 0);
        if (kc < 7) bc2 = *(const short8*)(cpb2 + (kc + 1) * 64); else bc2 = *(const short8*)cps2;
#pragma unroll
        for (int m = 0; m < 4; ++m)
            acc[m][3] = __builtin_amdgcn_mfma_f32_16x16x32_bf16(a[m], bc3, acc[m][3], 0, 0, 0);
        if (kc < 7) bc3 = *(const short8*)(cpb3 + (kc + 1) * 64); else bc3 = *(const short8*)cps3;
    }
    __builtin_amdgcn_s_barrier();   // all waves done reading Y branch half
    // epi-2 branch: h2b over Y[:,0:256]
#pragma unroll
    for (int m = 0; m < 4; ++m)
#pragma unroll
    for (int n = 0; n < 4; ++n) {
        int col = wid * 64 + n * 16 + arow;
#pragma unroll
        for (int r = 0; r < 4; ++r) {
            int row = m * 16 + (lane >> 4) * 4 + r;
            *(bhalf*)(Yb + yadr2(row, 2 * col)) = f2b(fmaxf(acc[m][n][r] + bi2b[n], 0.f));
            acc[m][n][r] = 0.f;
        }
    }
    wlgkm0();
    __builtin_amdgcn_s_barrier();
    // ---------------- L3 branch: wave w rows w*16.. , DOUT=3 ----------------
    {
        f32x4 z;
#pragma unroll
        for (int r = 0; r < 4; ++r) z[r] = 0.f;
        const int col3 = arow;
        for (int kc = 0; kc < 8; ++kc) {
            short8 a3 = *(const short8*)(Yb + yadr2(wid * 16 + arow, kc * 64 + koff));
            short8 bw;
#pragma unroll
            for (int j = 0; j < 8; ++j) bw[j] = 0;
            if (col3 < 3) {
                int kq = kc * 32 + (lane >> 4) * 8;
#pragma unroll
                for (int j = 0; j < 8; ++j)
                    bw[j] = (short)f2b(W3b[(kq + j) * 3 + col3]);
            }
            z = __builtin_amdgcn_mfma_f32_16x16x32_bf16(a3, bw, z, 0, 0, 0);
        }
        if (col3 < 3) {
            float bias = b3b[col3];
#pragma unroll
            for (int rr = 0; rr < 4; ++rr) {
                int r = wid * 16 + (lane >> 4) * 4 + rr;
                int p2 = tstart + r;
                if ((p2 - gbase) < gcnt) {
                    int ro = perm[p2];
                    float v = z[rr] + bias;
                    out[(size_t)ro * 3 + col3] = 1.f / (1.f + __expf(-v));
                }
            }
        }
    }
    // ---------------- L2 speed: reads Y[:,256:512] (untouched) --------------
    for (int kc = 0; kc < 8; ++kc) {
        short8 a[4];
#pragma unroll
        for (int m = 0; m < 4; ++m)
            a[m] = *(const short8*)(Yb + yadr2(m * 16 + arow, 512 + kc * 64 + koff));
#pragma unroll
        for (int m = 0; m < 4; ++m)
            acc[m][0] = __builtin_amdgcn_mfma_f32_16x16x32_bf16(a[m], bc0, acc[m][0], 0, 0, 0);
        if (kc < 7) bc0 = *(const short8*)(cps0 + (kc + 1) * 64);
#pragma unroll
        for (int m = 0; m < 4; ++m)
            acc[m][1] = __builtin_amdgcn_mfma_f32_16x16x32_bf16(a[m], bc1, acc[m][1], 0, 0, 0);
        if (kc < 7) bc1 = *(const short8*)(cps1 + (kc + 1) * 64);
#pragma unroll
        for (int m = 0; m < 4; ++m)
            acc[m][2] = __builtin_amdgcn_mfma_f32_16x16x32_bf16(a[m], bc2, acc[m][2], 0, 0, 0);
        if (kc < 7) bc2 = *(const short8*)(cps2 + (kc + 1) * 64);
#pragma unroll
        for (int m = 0; m < 4; ++m)
            acc[m][3] = __builtin_amdgcn_mfma_f32_16x16x32_bf16(a[m], bc3, acc[m][3], 0, 0, 0);
        if (kc < 7) bc3 = *(const short8*)(cps3 + (kc + 1) * 64);
    }
    __builtin_amdgcn_s_barrier();   // all waves done reading Y speed half
    // epi-2 speed: h2s over Y[:,256:512]
#pragma unroll
    for (int m = 0; m < 4; ++m)
#pragma unroll
    for (int n = 0; n < 4; ++n) {
        int col = 256 + wid * 64 + n * 16 + arow;
#pragma unroll
        for (int r = 0; r < 4; ++r) {
            int row = m * 16 + (lane >> 4) * 4 + r;
            *(bhalf*)(Yb + yadr2(row, 2 * col)) = f2b(fmaxf(acc[m][n][r] + bi2s[n], 0.f));
        }
    }
    wlgkm0();
    __builtin_amdgcn_s_barrier();
    // ---------------- L3 speed: DOUT=1 ----------------
    {
        f32x4 z;
#pragma unroll
        for (int r = 0; r < 4; ++r) z[r] = 0.f;
        const int col3 = arow;
        for (int kc = 0; kc < 8; ++kc) {
            short8 a3 = *(const short8*)(Yb + yadr2(wid * 16 + arow, 512 + kc * 64 + koff));
            short8 bw;
#pragma unroll
            for (int j = 0; j < 8; ++j) bw[j] = 0;
            if (col3 < 1) {
                int kq = kc * 32 + (lane >> 4) * 8;
#pragma unroll
                for (int j = 0; j < 8; ++j)
                    bw[j] = (short)f2b(Wso3[kq + j]);
            }
            z = __builtin_amdgcn_mfma_f32_16x16x32_bf16(a3, bw, z, 0, 0, 0);
        }
        if (col3 < 1) {
#pragma unroll
            for (int rr = 0; rr < 4; ++rr) {
                int r = wid * 16 + (lane >> 4) * 4 + rr;
                int p2 = tstart + r;
                if ((p2 - gbase) < gcnt) {
                    int ro = perm[p2];
                    out[(size_t)NB * 3 + ro] = z[rr] + bso3[0];
                }
            }
        }
    }
#undef ST_A
#undef ST_B
}

extern "C" void kernel_launch(void* const* d_in, const int* in_sizes, int n_in,
                              void* d_out, int out_size, void* d_ws, size_t ws_size,
                              hipStream_t stream) {
    (void)in_sizes; (void)n_in; (void)out_size; (void)ws_size;
    const float* emb   = (const float*)d_in[0];
    const float* speed = (const float*)d_in[1];
    const int*   cmd   = (const int*)d_in[2];
    const float* Wsi1  = (const float*)d_in[3];
    const float* bsi1  = (const float*)d_in[4];
    const float* Wsi2  = (const float*)d_in[5];
    const float* bsi2  = (const float*)d_in[6];
    const float* Wso1  = (const float*)d_in[7];
    const float* bso1  = (const float*)d_in[8];
    const float* Wso2  = (const float*)d_in[9];
    const float* bso2  = (const float*)d_in[10];
    const float* Wso3  = (const float*)d_in[11];
    const float* bso3  = (const float*)d_in[12];
    const float* Wb1   = (const float*)d_in[13];
    const float* bb1   = (const float*)d_in[14];
    const float* Wb2   = (const float*)d_in[15];
    const float* bb2   = (const float*)d_in[16];
    const float* Wb3   = (const float*)d_in[17];
    const float* bb3   = (const float*)d_in[18];
    float* out = (float*)d_out;

    char* ws = (char*)d_ws;
    bhalf* spb      = (bhalf*)(ws);
    int*   perm     = (int*)(ws + 16777216);
    int*   bcnt     = (int*)(ws + 17040896);
    int*   chunkoff = (int*)(ws + 17065472);
    int*   pad      = (int*)(ws + 17090048);
    bhalf* Wsi2T    = (bhalf*)(ws + 17090304);
    bhalf* Wso1T    = (bhalf*)(ws + 17155840);
    bhalf* Wso2T    = (bhalf*)(ws + 17483520);
    bhalf* Wb1T     = (bhalf*)(ws + 17614592);
    bhalf* Wb2T     = (bhalf*)(ws + 19580672);

    k_wprep<<<400, 256, 0, stream>>>(Wsi2, Wso1, Wso2, Wb1, Wb2,
                                     Wsi2T, Wso1T, Wso2T, Wb1T, Wb2T);
    k_prep<<<NB / 64, 256, 0, stream>>>(speed, Wsi1, bsi1, Wsi2T, bsi2, cmd,
                                        spb, bcnt);
    k_scan<<<1, 1024, 0, stream>>>(bcnt, chunkoff, pad);
    k_scatter<<<NB / 256, 256, 0, stream>>>(cmd, chunkoff, perm);
    k_head<<<NGRID, 256, 0, stream>>>(emb, spb,
                                      Wso1T, bso1, Wso2T, bso2, Wso3, bso3,
                                      Wb1T, bb1, Wb2T, bb2, Wb3, bb3,
                                      pad, perm, out);
}